// Round 7
// baseline (453.900 us; speedup 1.0000x reference)
//
#include <hip/hip_runtime.h>
#include <stdint.h>

typedef unsigned short u16;
typedef __attribute__((ext_vector_type(4))) float f32x4;
typedef __attribute__((ext_vector_type(8))) short bf16x8;
typedef bf16x8 bf16x8a __attribute__((may_alias));
typedef uint32_t u32a __attribute__((may_alias));

#define HID 1024
#define MLPD 4096
#define TEMB 1024
#define ADA_N 6144
#define SEQ 1024
#define BATCH 8
#define KCH 32          // ada split-K chunks
#define KCHLEN (TEMB / KCH)

// ---------- helpers ----------
__device__ __forceinline__ u16 f2bf_bits(float f) {
  uint32_t u = __float_as_uint(f);
  uint32_t r = (u + 0x7FFFu + ((u >> 16) & 1u)) >> 16;
  return (u16)r;
}

__device__ __forceinline__ float bf2f(u16 b) {
  return __uint_as_float(((uint32_t)b) << 16);
}

__device__ __forceinline__ uint32_t cvt_pk_bf16(float lo, float hi) {
  uint32_t r;
  asm("v_cvt_pk_bf16_f32 %0, %1, %2" : "=v"(r) : "v"(lo), "v"(hi));
  return r;
}

__device__ __forceinline__ float exp2_hw(float x) {
#if __has_builtin(__builtin_amdgcn_exp2f)
  return __builtin_amdgcn_exp2f(x);
#else
  return exp2f(x);
#endif
}

__device__ __forceinline__ void async_copy16(void* lds_dst, const void* g_src) {
  __builtin_amdgcn_global_load_lds(
      (const __attribute__((address_space(1))) void*)(uintptr_t)g_src,
      (__attribute__((address_space(3))) void*)(uint32_t)(uintptr_t)lds_dst,
      16, 0, 0);
}

__device__ __forceinline__ float gelu_tanh(float v) {
  float u = 0.7978845608028654f * (v + 0.044715f * v * v * v);
  float e = __expf(2.f * u);
  return v * e / (e + 1.f);   // = 0.5*v*(1+tanh(u))
}

// ---------- weight transpose fp32(KxN) -> bf16(NxK) ----------
__global__ __launch_bounds__(256) void transpose_bf16(const float* __restrict__ W,
                                                      u16* __restrict__ Wt, int K, int N) {
  __shared__ float tile[32][33];
  int n0 = blockIdx.x * 32, k0 = blockIdx.y * 32;
  int tx = threadIdx.x & 31, ty = threadIdx.x >> 5;   // 32 x 8
#pragma unroll
  for (int i = 0; i < 4; i++)
    tile[ty + i * 8][tx] = W[(size_t)(k0 + ty + i * 8) * N + n0 + tx];
  __syncthreads();
#pragma unroll
  for (int i = 0; i < 4; i++)
    Wt[(size_t)(n0 + ty + i * 8) * K + k0 + tx] = f2bf_bits(tile[tx][ty + i * 8]);
}

// ---------- ada split-K ----------
__global__ __launch_bounds__(256) void ada_part(const float* __restrict__ c,
                                                const float* __restrict__ W,
                                                float* __restrict__ part) {
  __shared__ float sc[BATCH * KCHLEN];
  int t = threadIdx.x;
  int col = blockIdx.x * 256 + t;
  int kc = blockIdx.y;
  int k0 = kc * KCHLEN;
  for (int i = t; i < BATCH * KCHLEN; i += 256) {
    int b = i >> 5, kk = i & (KCHLEN - 1);
    float v = c[b * TEMB + k0 + kk];
    sc[i] = v / (1.f + __expf(-v));
  }
  __syncthreads();
  float acc[BATCH] = {};
  for (int kk = 0; kk < KCHLEN; kk++) {
    float w = W[(size_t)(k0 + kk) * ADA_N + col];
#pragma unroll
    for (int b = 0; b < BATCH; b++) acc[b] += sc[b * KCHLEN + kk] * w;
  }
#pragma unroll
  for (int b = 0; b < BATCH; b++)
    part[((size_t)kc * BATCH + b) * ADA_N + col] = acc[b];
}

__global__ __launch_bounds__(256) void ada_reduce(const float* __restrict__ part,
                                                  const float* __restrict__ bias,
                                                  float* __restrict__ out) {
  int i = blockIdx.x * 256 + threadIdx.x;   // over 8*6144
  int col = i % ADA_N, b = i / ADA_N;
  float s = bias[col];
#pragma unroll
  for (int kc = 0; kc < KCH; kc++)
    s += part[((size_t)kc * BATCH + b) * ADA_N + col];
  out[(size_t)b * ADA_N + col] = s;
}

// ---------- fused LayerNorm + modulate -> bf16 ----------
__global__ __launch_bounds__(256) void ln_mod(const float* __restrict__ x,
                                              const float* __restrict__ ada,
                                              int shift_off, int scale_off,
                                              u16* __restrict__ h) {
  int row = blockIdx.x;        // 0..8191
  int bb = row >> 10;
  int t = threadIdx.x;
  const float4 v = ((const float4*)(x + (size_t)row * HID))[t];
  float s = v.x + v.y + v.z + v.w;
  float sq = v.x * v.x + v.y * v.y + v.z * v.z + v.w * v.w;
#pragma unroll
  for (int off = 32; off >= 1; off >>= 1) {
    s += __shfl_xor(s, off);
    sq += __shfl_xor(sq, off);
  }
  __shared__ float red[8];
  int wid = t >> 6;
  if ((t & 63) == 0) { red[wid] = s; red[4 + wid] = sq; }
  __syncthreads();
  s = red[0] + red[1] + red[2] + red[3];
  sq = red[4] + red[5] + red[6] + red[7];
  float mu = s * (1.0f / HID);
  float rs = rsqrtf(sq * (1.0f / HID) - mu * mu + 1e-6f);
  const float4 sc = ((const float4*)(ada + (size_t)bb * ADA_N + scale_off))[t];
  const float4 sh = ((const float4*)(ada + (size_t)bb * ADA_N + shift_off))[t];
  ushort4 o;
  o.x = f2bf_bits((v.x - mu) * rs * (1.f + sc.x) + sh.x);
  o.y = f2bf_bits((v.y - mu) * rs * (1.f + sc.y) + sh.y);
  o.z = f2bf_bits((v.z - mu) * rs * (1.f + sc.z) + sh.z);
  o.w = f2bf_bits((v.w - mu) * rs * (1.f + sc.w) + sh.w);
  ((ushort4*)(h + (size_t)row * HID))[t] = o;
}

// ---------- counted-prefetch 256x128 bf16 GEMM ----------
// C(M x N) = A(M x K) * Bt(N x K)^T + bias. 512 thr / 8 waves (2M x 4N), BK=64.
// Per K-tile: vmcnt(6) [counted: next tile's loads stay in flight] -> barrier ->
// ALL 20 frag ds_reads (compiler-scheduled, no order pins) -> lgkmcnt(0) ->
// barrier -> stage tile t+2 into the just-drained buffer -> setprio(1) ->
// 32 MFMA -> setprio(0). No mid-loop vmcnt(0) drains, no sched_barrier pinning.
// Epilogue: acc -> bf16 -> LDS [256][132] transpose -> 16-B coalesced stores.
// EPI: 0 = bf16 out, 1 = gelu -> bf16 out, 2 = f32 out = resid + gate*(acc+bias)

template <int NLOAD>
__device__ __forceinline__ void stage_tile(u16* dst, const u16* gsrc, int K, int koff, int t) {
#pragma unroll
  for (int i = 0; i < NLOAD; ++i) {
    int slot = i * 512 + t;
    int row = slot >> 3, cp = slot & 7;
    const u16* src = gsrc + (size_t)row * K + koff + ((cp ^ (row & 7)) << 3);
    async_copy16(dst + slot * 8, src);
  }
}

#define LDSRD(buf, row, kk) \
  (*(const bf16x8a*)&(buf)[(row) * 64 + ((((kk) * 4 + l4) ^ ((row) & 7)) << 3)])

template <int EPI>
__global__ __launch_bounds__(512, 2) void gemm8(const u16* __restrict__ A,
                                                const u16* __restrict__ Bt,
                                                const float* __restrict__ bias,
                                                void* __restrict__ Cout,
                                                const float* __restrict__ resid,
                                                const float* __restrict__ gate,
                                                int N, int K) {
  __shared__ u16 lds[49152];          // 96 KB: As0|As1|Bs0|Bs1; reused by epilogue
  u16* const As0 = lds;               // 256x64
  u16* const As1 = lds + 16384;
  u16* const Bs0 = lds + 32768;       // 128x64
  u16* const Bs1 = lds + 40960;

  int t = threadIdx.x;
  int lane = t & 63, wid = t >> 6;
  int l15 = lane & 15, l4 = lane >> 4;
  int wr = wid >> 2, wc = wid & 3;    // 2 x 4 waves; wave tile 128 x 32
  // XCD m-banding: 4 m-tiles per XCD (A-band L2-resident)
  int lid = blockIdx.x;
  int xcd = lid & 7, win = lid >> 3;
  int m0 = (xcd * 4 + (win & 3)) * 256;
  int n0 = (win >> 2) * 128;

  const u16* Abase = A + (size_t)m0 * K;
  const u16* Bbase = Bt + (size_t)n0 * K;
  f32x4 acc[8][2] = {};

  stage_tile<4>(As0, Abase, K, 0, t);
  stage_tile<2>(Bs0, Bbase, K, 0, t);
  stage_tile<4>(As1, Abase, K, 64, t);
  stage_tile<2>(Bs1, Bbase, K, 64, t);
  int nt = K / 64;
  for (int ts = 0; ts < nt; ++ts) {
    u16* cA = (ts & 1) ? As1 : As0;
    u16* cB = (ts & 1) ? Bs1 : Bs0;
    if (ts == nt - 1) asm volatile("s_waitcnt vmcnt(0)" ::: "memory");
    else              asm volatile("s_waitcnt vmcnt(6)" ::: "memory");
    __builtin_amdgcn_s_barrier();     // all waves' tile-ts data landed
    asm volatile("" ::: "memory");
    bf16x8 bf[2][2], af[8][2];
#pragma unroll
    for (int ni = 0; ni < 2; ++ni)
#pragma unroll
      for (int kk = 0; kk < 2; ++kk)
        bf[ni][kk] = LDSRD(cB, wc * 32 + ni * 16 + l15, kk);
#pragma unroll
    for (int mi = 0; mi < 8; ++mi)
#pragma unroll
      for (int kk = 0; kk < 2; ++kk)
        af[mi][kk] = LDSRD(cA, wr * 128 + mi * 16 + l15, kk);
    asm volatile("s_waitcnt lgkmcnt(0)" ::: "memory");   // my reads complete
    __builtin_amdgcn_s_barrier();     // ALL waves' reads complete -> buffer dead
    if (ts + 2 < nt) {
      stage_tile<4>(cA, Abase, K, (ts + 2) * 64, t);     // overwrite with t+2
      stage_tile<2>(cB, Bbase, K, (ts + 2) * 64, t);
    }
    __builtin_amdgcn_s_setprio(1);
#pragma unroll
    for (int mi = 0; mi < 8; ++mi)
#pragma unroll
      for (int ni = 0; ni < 2; ++ni) {
        acc[mi][ni] = __builtin_amdgcn_mfma_f32_16x16x32_bf16(af[mi][0], bf[ni][0], acc[mi][ni], 0, 0, 0);
        acc[mi][ni] = __builtin_amdgcn_mfma_f32_16x16x32_bf16(af[mi][1], bf[ni][1], acc[mi][ni], 0, 0, 0);
      }
    __builtin_amdgcn_s_setprio(0);
  }

  // ---- epilogue: acc -> bf16 -> LDS transpose -> vectorized stores ----
  const int EST = 132;                 // u16 stride: 264 B -> ~2-way banks
  int bb = m0 >> 10;                   // 256-row tile lies within one batch
#pragma unroll
  for (int ni = 0; ni < 2; ++ni) {
    int col = wc * 32 + ni * 16 + l15;
    float bv = bias[n0 + col];
    float gv = (EPI == 2) ? gate[(size_t)bb * ADA_N + n0 + col] : 0.f;
#pragma unroll
    for (int mi = 0; mi < 8; ++mi)
#pragma unroll
      for (int r = 0; r < 4; ++r) {
        int row = wr * 128 + mi * 16 + l4 * 4 + r;
        float v = acc[mi][ni][r] + bv;
        if (EPI == 1) v = gelu_tanh(v);
        if (EPI == 2) v = gv * v;
        lds[row * EST + col] = f2bf_bits(v);
      }
  }
  asm volatile("s_waitcnt lgkmcnt(0)" ::: "memory");
  __builtin_amdgcn_s_barrier();
  asm volatile("" ::: "memory");
  {
    int row = t >> 1, half = t & 1;    // 2 threads per row
    size_t grow = (size_t)(m0 + row) * N + n0 + half * 64;
#pragma unroll
    for (int j = 0; j < 8; ++j) {
      bf16x8 v = *(const bf16x8a*)&lds[row * EST + half * 64 + j * 8];
      if (EPI == 2) {
        const float4* rp = (const float4*)&resid[grow + j * 8];
        float4 o0 = rp[0], o1 = rp[1];
        o0.x += bf2f((u16)v[0]); o0.y += bf2f((u16)v[1]);
        o0.z += bf2f((u16)v[2]); o0.w += bf2f((u16)v[3]);
        o1.x += bf2f((u16)v[4]); o1.y += bf2f((u16)v[5]);
        o1.z += bf2f((u16)v[6]); o1.w += bf2f((u16)v[7]);
        float4* op = (float4*)((float*)Cout + grow + j * 8);
        op[0] = o0; op[1] = o1;
      } else {
        *(bf16x8a*)((u16*)Cout + grow + j * 8) = v;
      }
    }
  }
}

// ---------- flash attention, swapped-operand structure ----------
__global__ __launch_bounds__(256, 3) void attn_kernel(const u16* __restrict__ qkv,
                                                      u16* __restrict__ O) {
  const int KSTR = 72, VSTR = 72, PSTR = 72;  // u16 strides, 16B-aligned rows
  __shared__ u16 Ks[64 * 72];       // K chunk rows [kv][d]
  __shared__ u16 Vt[64 * 72];       // V chunk transposed [d][kv]
  __shared__ u16 Plds[4 * 16 * 72]; // per-wave P rows [q][kv]
  int t = threadIdx.x, lane = t & 63, wid = t >> 6;
  int l15 = lane & 15, l4 = lane >> 4;
  // T1: all 8 q-tiles of one (b,h) + 16 consecutive bh land on one XCD (KV L2 reuse)
  int work = ((blockIdx.x & 7) << 7) + (blockIdx.x >> 3);   // nwg = 1024
  int bh = work >> 3, qt8 = work & 7;
  int b = bh >> 4, h = bh & 15;
  int bRow = b * SEQ;
  int hOff = h * 64;
  int q0 = qt8 * 128 + wid * 32;

  // Q fragments (B-operand): lane l15 = q-row, k = d = l4*8+e
  bf16x8 qr[2][2];
#pragma unroll
  for (int qt = 0; qt < 2; qt++) {
    const u16* qbase = qkv + (size_t)(bRow + q0 + qt * 16 + l15) * 3072 + hOff;
    qr[qt][0] = *(const bf16x8a*)(qbase + l4 * 8);
    qr[qt][1] = *(const bf16x8a*)(qbase + 32 + l4 * 8);
  }

  const float csc = 0.125f * 1.4426950408889634f;  // scale * log2(e)
  float mrow[2] = {-1e30f, -1e30f};
  float lsum[2] = {0.f, 0.f};
  f32x4 o[2][4] = {};   // O^T: [qt][dt], lane: q=l15 (col), d=dt*16+l4*4+r (row)
  u16* pw = Plds + wid * 16 * PSTR;

  for (int cc = 0; cc < 16; cc++) {
    int kv0 = cc * 64;
    __syncthreads();
    // stage K rows (row-major, padded)
#pragma unroll
    for (int i = 0; i < 2; i++) {
      int idx = i * 256 + t;
      int row = idx >> 3, ch = idx & 7;
      bf16x8 kk = *(const bf16x8a*)(qkv + (size_t)(bRow + kv0 + row) * 3072 + 1024 + hOff + ch * 8);
      *(bf16x8a*)&Ks[row * KSTR + ch * 8] = kk;
    }
    // stage V transposed (dc-staggered scalar writes)
#pragma unroll
    for (int i = 0; i < 2; i++) {
      int idx = i * 256 + t;
      int kv = idx >> 3, dc = idx & 7;
      bf16x8 vv = *(const bf16x8a*)(qkv + (size_t)(bRow + kv0 + kv) * 3072 + 2048 + hOff + dc * 8);
#pragma unroll
      for (int j = 0; j < 8; j++) {
        int jj = (j + dc) & 7;
        Vt[(dc * 8 + jj) * VSTR + kv] = ((const u16*)&vv)[jj];
      }
    }
    __syncthreads();

    // K A-fragments: lane l15 = kv-row, k = d
    bf16x8 ak[4][2];
#pragma unroll
    for (int kt = 0; kt < 4; kt++) {
      ak[kt][0] = *(const bf16x8a*)&Ks[(kt * 16 + l15) * KSTR + l4 * 8];
      ak[kt][1] = *(const bf16x8a*)&Ks[(kt * 16 + l15) * KSTR + 32 + l4 * 8];
    }
    // S^T = K . Q^T (raw, unscaled)
    f32x4 st[2][4];
#pragma unroll
    for (int qt = 0; qt < 2; qt++)
#pragma unroll
      for (int kt = 0; kt < 4; kt++) {
        f32x4 z = {0.f, 0.f, 0.f, 0.f};
        z = __builtin_amdgcn_mfma_f32_16x16x32_bf16(ak[kt][0], qr[qt][0], z, 0, 0, 0);
        z = __builtin_amdgcn_mfma_f32_16x16x32_bf16(ak[kt][1], qr[qt][1], z, 0, 0, 0);
        st[qt][kt] = z;
      }
    // V^T A-fragments: lane l15 = d-row, k = kv
    bf16x8 av[4][2];
#pragma unroll
    for (int dt = 0; dt < 4; dt++) {
      av[dt][0] = *(const bf16x8a*)&Vt[(dt * 16 + l15) * VSTR + l4 * 8];
      av[dt][1] = *(const bf16x8a*)&Vt[(dt * 16 + l15) * VSTR + 32 + l4 * 8];
    }

#pragma unroll
    for (int qt = 0; qt < 2; qt++) {
      float mx = st[qt][0][0];
#pragma unroll
      for (int kt = 0; kt < 4; kt++)
#pragma unroll
        for (int r = 0; r < 4; r++) mx = fmaxf(mx, st[qt][kt][r]);
      mx = fmaxf(mx, __shfl_xor(mx, 16));
      mx = fmaxf(mx, __shfl_xor(mx, 32));
      float mn = fmaxf(mrow[qt], mx * csc);
      float al = exp2_hw(mrow[qt] - mn);
      mrow[qt] = mn;
      float rs = 0.f;
#pragma unroll
      for (int kt = 0; kt < 4; kt++)
#pragma unroll
        for (int r = 0; r < 4; r++) {
          float p = exp2_hw(__builtin_fmaf(st[qt][kt][r], csc, -mn));
          st[qt][kt][r] = p;
          rs += p;
        }
      rs += __shfl_xor(rs, 16);
      rs += __shfl_xor(rs, 32);
      lsum[qt] = lsum[qt] * al + rs;
#pragma unroll
      for (int dt = 0; dt < 4; dt++) o[qt][dt] *= al;
      // P -> LDS row q=l15 via packed bf16 writes (may_alias: keeps TBAA ordering)
#pragma unroll
      for (int kt = 0; kt < 4; kt++) {
#pragma unroll
        for (int hh = 0; hh < 2; hh++) {
          uint32_t pk = cvt_pk_bf16(st[qt][kt][2 * hh], st[qt][kt][2 * hh + 1]);
          *(u32a*)&pw[l15 * PSTR + kt * 16 + l4 * 4 + 2 * hh] = pk;
        }
      }
      // hard fence: P writes must complete before P fragment reads (rule 18 pattern)
      asm volatile("s_waitcnt lgkmcnt(0)" ::: "memory");
      __builtin_amdgcn_sched_barrier(0);
      // P B-fragments: lane l15 = q-row, k = kv
      bf16x8 bp0 = *(const bf16x8a*)&pw[l15 * PSTR + l4 * 8];
      bf16x8 bp1 = *(const bf16x8a*)&pw[l15 * PSTR + 32 + l4 * 8];
#pragma unroll
      for (int dt = 0; dt < 4; dt++) {
        o[qt][dt] = __builtin_amdgcn_mfma_f32_16x16x32_bf16(av[dt][0], bp0, o[qt][dt], 0, 0, 0);
        o[qt][dt] = __builtin_amdgcn_mfma_f32_16x16x32_bf16(av[dt][1], bp1, o[qt][dt], 0, 0, 0);
      }
      // P reads of this qt must finish before next qt overwrites pw
      asm volatile("s_waitcnt lgkmcnt(0)" ::: "memory");
      __builtin_amdgcn_sched_barrier(0);
    }
  }
  // epilogue: O^T lane holds q=l15, d = dt*16 + l4*4 + {0..3}
#pragma unroll
  for (int qt = 0; qt < 2; qt++) {
    float inv = 1.f / lsum[qt];
    u16* orow = O + (size_t)(bRow + q0 + qt * 16 + l15) * HID + hOff;
#pragma unroll
    for (int dt = 0; dt < 4; dt++) {
      uint2 w;
      w.x = cvt_pk_bf16(o[qt][dt][0] * inv, o[qt][dt][1] * inv);
      w.y = cvt_pk_bf16(o[qt][dt][2] * inv, o[qt][dt][3] * inv);
      *(uint2*)(orow + dt * 16 + l4 * 4) = w;
    }
  }
}

// ---------- launch ----------
extern "C" void kernel_launch(void* const* d_in, const int* in_sizes, int n_in,
                              void* d_out, int out_size, void* d_ws, size_t ws_size,
                              hipStream_t stream) {
  const float* x      = (const float*)d_in[0];
  const float* c      = (const float*)d_in[1];
  const float* W_qkv  = (const float*)d_in[2];
  const float* b_qkv  = (const float*)d_in[3];
  const float* W_proj = (const float*)d_in[4];
  const float* b_proj = (const float*)d_in[5];
  const float* W_fc1  = (const float*)d_in[6];
  const float* b_fc1  = (const float*)d_in[7];
  const float* W_fc2  = (const float*)d_in[8];
  const float* b_fc2  = (const float*)d_in[9];
  const float* W_ada  = (const float*)d_in[10];
  const float* b_ada  = (const float*)d_in[11];
  float* out = (float*)d_out;
  char* ws = (char*)d_ws;

  // workspace layout (bytes)
  float* ada  = (float*)(ws + 0);            // 8x6144 f32
  u16* WtQKV  = (u16*)(ws + 196608);         // 3072x1024 bf16
  u16* WtP    = (u16*)(ws + 6488064);        // 1024x1024 bf16
  u16* WtF1   = (u16*)(ws + 8585216);        // 4096x1024 bf16
  u16* WtF2   = (u16*)(ws + 16973824);       // 1024x4096 bf16
  u16* hbuf   = (u16*)(ws + 25362432);       // 8192x1024 bf16 (h / attnO / h2)
  u16* big    = (u16*)(ws + 42139648);       // 8192x4096 bf16 max (qkv / gelu-out)
  // ada split-K partials live inside `big` (only used before qkv GEMM writes it)
  float* apart = (float*)(ws + 42139648);    // 32x8x6144 f32 = 6.29 MB

  transpose_bf16<<<dim3(3072 / 32, 1024 / 32), 256, 0, stream>>>(W_qkv, WtQKV, 1024, 3072);
  transpose_bf16<<<dim3(1024 / 32, 1024 / 32), 256, 0, stream>>>(W_proj, WtP, 1024, 1024);
  transpose_bf16<<<dim3(4096 / 32, 1024 / 32), 256, 0, stream>>>(W_fc1, WtF1, 1024, 4096);
  transpose_bf16<<<dim3(1024 / 32, 4096 / 32), 256, 0, stream>>>(W_fc2, WtF2, 4096, 1024);
  ada_part<<<dim3(ADA_N / 256, KCH), 256, 0, stream>>>(c, W_ada, apart);
  ada_reduce<<<(BATCH * ADA_N) / 256, 256, 0, stream>>>(apart, b_ada, ada);
  ln_mod<<<8192, 256, 0, stream>>>(x, ada, 0, 1024, hbuf);
  // qkv: 32 m-tiles x 24 n-tiles = 768 blocks (3 full CU rounds)
  gemm8<0><<<768, 512, 0, stream>>>(hbuf, WtQKV, b_qkv, big, nullptr, nullptr, 3072, 1024);
  attn_kernel<<<1024, 256, 0, stream>>>(big, hbuf);
  // proj: 32 x 8 = 256 blocks (1 round)
  gemm8<2><<<256, 512, 0, stream>>>(hbuf, WtP, b_proj, out, x, ada + 2048, 1024, 1024);
  ln_mod<<<8192, 256, 0, stream>>>(out, ada, 3072, 4096, hbuf);
  // fc1: 32 x 32 = 1024 blocks (4 rounds)
  gemm8<1><<<1024, 512, 0, stream>>>(hbuf, WtF1, b_fc1, big, nullptr, nullptr, 4096, 1024);
  // fc2: 32 x 8 = 256 blocks (1 round), K=4096
  gemm8<2><<<256, 512, 0, stream>>>(big, WtF2, b_fc2, out, out, ada + 5120, 1024, 4096);
}

// Round 8
// 429.748 us; speedup vs baseline: 1.0562x; 1.0562x over previous
//
#include <hip/hip_runtime.h>
#include <stdint.h>

typedef unsigned short u16;
typedef __attribute__((ext_vector_type(4))) float f32x4;
typedef __attribute__((ext_vector_type(8))) short bf16x8;
typedef bf16x8 bf16x8a __attribute__((may_alias));
typedef uint32_t u32a __attribute__((may_alias));

#define HID 1024
#define MLPD 4096
#define TEMB 1024
#define ADA_N 6144
#define SEQ 1024
#define BATCH 8
#define KCH 32          // ada split-K chunks
#define KCHLEN (TEMB / KCH)

// ---------- helpers ----------
__device__ __forceinline__ u16 f2bf_bits(float f) {
  uint32_t u = __float_as_uint(f);
  uint32_t r = (u + 0x7FFFu + ((u >> 16) & 1u)) >> 16;
  return (u16)r;
}

__device__ __forceinline__ float bf2f(u16 b) {
  return __uint_as_float(((uint32_t)b) << 16);
}

__device__ __forceinline__ uint32_t cvt_pk_bf16(float lo, float hi) {
  uint32_t r;
  asm("v_cvt_pk_bf16_f32 %0, %1, %2" : "=v"(r) : "v"(lo), "v"(hi));
  return r;
}

__device__ __forceinline__ float exp2_hw(float x) {
#if __has_builtin(__builtin_amdgcn_exp2f)
  return __builtin_amdgcn_exp2f(x);
#else
  return exp2f(x);
#endif
}

__device__ __forceinline__ void async_copy16(void* lds_dst, const void* g_src) {
  __builtin_amdgcn_global_load_lds(
      (const __attribute__((address_space(1))) void*)(uintptr_t)g_src,
      (__attribute__((address_space(3))) void*)(uint32_t)(uintptr_t)lds_dst,
      16, 0, 0);
}

__device__ __forceinline__ float gelu_tanh(float v) {
  float u = 0.7978845608028654f * (v + 0.044715f * v * v * v);
  float e = __expf(2.f * u);
  return v * e / (e + 1.f);   // = 0.5*v*(1+tanh(u))
}

// ---------- weight transpose fp32(KxN) -> bf16(NxK) ----------
__global__ __launch_bounds__(256) void transpose_bf16(const float* __restrict__ W,
                                                      u16* __restrict__ Wt, int K, int N) {
  __shared__ float tile[32][33];
  int n0 = blockIdx.x * 32, k0 = blockIdx.y * 32;
  int tx = threadIdx.x & 31, ty = threadIdx.x >> 5;   // 32 x 8
#pragma unroll
  for (int i = 0; i < 4; i++)
    tile[ty + i * 8][tx] = W[(size_t)(k0 + ty + i * 8) * N + n0 + tx];
  __syncthreads();
#pragma unroll
  for (int i = 0; i < 4; i++)
    Wt[(size_t)(n0 + ty + i * 8) * K + k0 + tx] = f2bf_bits(tile[tx][ty + i * 8]);
}

// ---------- ada split-K ----------
__global__ __launch_bounds__(256) void ada_part(const float* __restrict__ c,
                                                const float* __restrict__ W,
                                                float* __restrict__ part) {
  __shared__ float sc[BATCH * KCHLEN];
  int t = threadIdx.x;
  int col = blockIdx.x * 256 + t;
  int kc = blockIdx.y;
  int k0 = kc * KCHLEN;
  for (int i = t; i < BATCH * KCHLEN; i += 256) {
    int b = i >> 5, kk = i & (KCHLEN - 1);
    float v = c[b * TEMB + k0 + kk];
    sc[i] = v / (1.f + __expf(-v));
  }
  __syncthreads();
  float acc[BATCH] = {};
  for (int kk = 0; kk < KCHLEN; kk++) {
    float w = W[(size_t)(k0 + kk) * ADA_N + col];
#pragma unroll
    for (int b = 0; b < BATCH; b++) acc[b] += sc[b * KCHLEN + kk] * w;
  }
#pragma unroll
  for (int b = 0; b < BATCH; b++)
    part[((size_t)kc * BATCH + b) * ADA_N + col] = acc[b];
}

__global__ __launch_bounds__(256) void ada_reduce(const float* __restrict__ part,
                                                  const float* __restrict__ bias,
                                                  float* __restrict__ out) {
  int i = blockIdx.x * 256 + threadIdx.x;   // over 8*6144
  int col = i % ADA_N, b = i / ADA_N;
  float s = bias[col];
#pragma unroll
  for (int kc = 0; kc < KCH; kc++)
    s += part[((size_t)kc * BATCH + b) * ADA_N + col];
  out[(size_t)b * ADA_N + col] = s;
}

// ---------- fused LayerNorm + modulate -> bf16 ----------
__global__ __launch_bounds__(256) void ln_mod(const float* __restrict__ x,
                                              const float* __restrict__ ada,
                                              int shift_off, int scale_off,
                                              u16* __restrict__ h) {
  int row = blockIdx.x;        // 0..8191
  int bb = row >> 10;
  int t = threadIdx.x;
  const float4 v = ((const float4*)(x + (size_t)row * HID))[t];
  float s = v.x + v.y + v.z + v.w;
  float sq = v.x * v.x + v.y * v.y + v.z * v.z + v.w * v.w;
#pragma unroll
  for (int off = 32; off >= 1; off >>= 1) {
    s += __shfl_xor(s, off);
    sq += __shfl_xor(sq, off);
  }
  __shared__ float red[8];
  int wid = t >> 6;
  if ((t & 63) == 0) { red[wid] = s; red[4 + wid] = sq; }
  __syncthreads();
  s = red[0] + red[1] + red[2] + red[3];
  sq = red[4] + red[5] + red[6] + red[7];
  float mu = s * (1.0f / HID);
  float rs = rsqrtf(sq * (1.0f / HID) - mu * mu + 1e-6f);
  const float4 sc = ((const float4*)(ada + (size_t)bb * ADA_N + scale_off))[t];
  const float4 sh = ((const float4*)(ada + (size_t)bb * ADA_N + shift_off))[t];
  ushort4 o;
  o.x = f2bf_bits((v.x - mu) * rs * (1.f + sc.x) + sh.x);
  o.y = f2bf_bits((v.y - mu) * rs * (1.f + sc.y) + sh.y);
  o.z = f2bf_bits((v.z - mu) * rs * (1.f + sc.z) + sh.z);
  o.w = f2bf_bits((v.w - mu) * rs * (1.f + sc.w) + sh.w);
  ((ushort4*)(h + (size_t)row * HID))[t] = o;
}

// ---------- 2-phase 128x128 bf16 GEMM (round-5 schedule + swizzle + vec epilogue) ----------
// C(M x N) = A(M x K) * Bt(N x K)^T + bias. 256 thr / 4 waves (2x2), BK=32.
// Per K-tile: stage(t+1 into other buf) -> vmcnt(4) [counted: prefetch stays
// in flight] -> s_barrier -> compiler-interleaved 8 ds_read + 16 MFMA ->
// s_barrier. LDS rows are 64 B; swizzle key (row>>1)&3 over 4 16-B chunks
// (2-way banks = free), applied on BOTH gld-lds source and ds_read (rule 21).
// Epilogue: acc -> (bias/gelu/gate) -> bf16 -> LDS [128][132] -> 16-B stores.
// EPI: 0 = bf16 out, 1 = gelu -> bf16 out, 2 = f32 out = resid + gate*(acc+bias)

__device__ __forceinline__ void stage32(u16* dst, const u16* gsrc, int K, int koff, int t) {
#pragma unroll
  for (int i = 0; i < 2; ++i) {
    int slot = i * 256 + t;
    int row = slot >> 2, cp = slot & 3;
    const u16* src = gsrc + (size_t)row * K + koff + ((cp ^ ((row >> 1) & 3)) << 3);
    async_copy16(dst + slot * 8, src);
  }
}

#define LDSRD32(buf, row) \
  (*(const bf16x8a*)&(buf)[(row) * 32 + ((l4 ^ (((row) >> 1) & 3)) << 3)])

template <int EPI>
__global__ __launch_bounds__(256) void gemm2(const u16* __restrict__ A,
                                             const u16* __restrict__ Bt,
                                             const float* __restrict__ bias,
                                             void* __restrict__ Cout,
                                             const float* __restrict__ resid,
                                             const float* __restrict__ gate,
                                             int N, int K) {
  __shared__ u16 lds[16896];           // 33 KB; staging (32 KB) then epilogue 128x132
  u16* const As0 = lds;                // 128x32 each (8 KB)
  u16* const As1 = lds + 4096;
  u16* const Bs0 = lds + 8192;
  u16* const Bs1 = lds + 12288;

  int t = threadIdx.x;
  int lane = t & 63, wid = t >> 6;
  int l15 = lane & 15, l4 = lane >> 4;
  int wr = wid >> 1, wc = wid & 1;     // 2 x 2 waves; wave tile 64 x 64
  // XCD m-banding: each XCD owns 8 contiguous m-tiles; n sweeps within band.
  int lid = blockIdx.x;
  int xcd = lid & 7, win = lid >> 3;
  int m0 = (xcd * 8 + (win & 7)) * 128;
  int n0 = (win >> 3) * 128;

  const u16* Abase = A + (size_t)m0 * K;
  const u16* Bbase = Bt + (size_t)n0 * K;
  f32x4 acc[4][4] = {};

  stage32(As0, Abase, K, 0, t);
  stage32(Bs0, Bbase, K, 0, t);
  int nt = K / 32;
  for (int ts = 0; ts < nt; ++ts) {
    u16* cA = (ts & 1) ? As1 : As0;
    u16* cB = (ts & 1) ? Bs1 : Bs0;
    if (ts + 1 < nt) {
      stage32((ts & 1) ? As0 : As1, Abase, K, (ts + 1) * 32, t);
      stage32((ts & 1) ? Bs0 : Bs1, Bbase, K, (ts + 1) * 32, t);
      asm volatile("s_waitcnt vmcnt(4)" ::: "memory");   // cur landed; prefetch in flight
    } else {
      asm volatile("s_waitcnt vmcnt(0)" ::: "memory");
    }
    __builtin_amdgcn_s_barrier();
    bf16x8 af[4], bfr[4];
#pragma unroll
    for (int mi = 0; mi < 4; ++mi)
      af[mi] = LDSRD32(cA, wr * 64 + mi * 16 + l15);
#pragma unroll
    for (int ni = 0; ni < 4; ++ni)
      bfr[ni] = LDSRD32(cB, wc * 64 + ni * 16 + l15);
#pragma unroll
    for (int mi = 0; mi < 4; ++mi)
#pragma unroll
      for (int ni = 0; ni < 4; ++ni)
        acc[mi][ni] = __builtin_amdgcn_mfma_f32_16x16x32_bf16(af[mi], bfr[ni], acc[mi][ni], 0, 0, 0);
    asm volatile("" ::: "memory");
    __builtin_amdgcn_s_barrier();      // all waves' reads done -> buffers reusable
  }

  // ---- epilogue: acc -> bf16 -> LDS transpose -> 16-B coalesced stores ----
  const int EST = 132;
  int bb = m0 >> 10;                   // 128-row tile lies within one batch
#pragma unroll
  for (int ni = 0; ni < 4; ++ni) {
    int col = wc * 64 + ni * 16 + l15;
    float bv = bias[n0 + col];
    float gv = (EPI == 2) ? gate[(size_t)bb * ADA_N + n0 + col] : 0.f;
#pragma unroll
    for (int mi = 0; mi < 4; ++mi)
#pragma unroll
      for (int r = 0; r < 4; ++r) {
        int row = wr * 64 + mi * 16 + l4 * 4 + r;
        float v = acc[mi][ni][r] + bv;
        if (EPI == 1) v = gelu_tanh(v);
        if (EPI == 2) v = gv * v;
        lds[row * EST + col] = f2bf_bits(v);
      }
  }
  asm volatile("s_waitcnt lgkmcnt(0)" ::: "memory");
  __builtin_amdgcn_s_barrier();
  asm volatile("" ::: "memory");
  {
    int row = t >> 1, half = t & 1;    // 2 threads per 128-col row
    size_t grow = (size_t)(m0 + row) * N + n0 + half * 64;
#pragma unroll
    for (int j = 0; j < 8; ++j) {
      bf16x8 v = *(const bf16x8a*)&lds[row * EST + half * 64 + j * 8];
      if (EPI == 2) {
        const float4* rp = (const float4*)&resid[grow + j * 8];
        float4 o0 = rp[0], o1 = rp[1];
        o0.x += bf2f((u16)v[0]); o0.y += bf2f((u16)v[1]);
        o0.z += bf2f((u16)v[2]); o0.w += bf2f((u16)v[3]);
        o1.x += bf2f((u16)v[4]); o1.y += bf2f((u16)v[5]);
        o1.z += bf2f((u16)v[6]); o1.w += bf2f((u16)v[7]);
        float4* op = (float4*)((float*)Cout + grow + j * 8);
        op[0] = o0; op[1] = o1;
      } else {
        *(bf16x8a*)((u16*)Cout + grow + j * 8) = v;
      }
    }
  }
}

// ---------- flash attention, swapped-operand structure ----------
__global__ __launch_bounds__(256, 3) void attn_kernel(const u16* __restrict__ qkv,
                                                      u16* __restrict__ O) {
  const int KSTR = 72, VSTR = 72, PSTR = 72;  // u16 strides, 16B-aligned rows
  __shared__ u16 Ks[64 * 72];       // K chunk rows [kv][d]
  __shared__ u16 Vt[64 * 72];       // V chunk transposed [d][kv]
  __shared__ u16 Plds[4 * 16 * 72]; // per-wave P rows [q][kv]
  int t = threadIdx.x, lane = t & 63, wid = t >> 6;
  int l15 = lane & 15, l4 = lane >> 4;
  // T1: all 8 q-tiles of one (b,h) + 16 consecutive bh land on one XCD (KV L2 reuse)
  int work = ((blockIdx.x & 7) << 7) + (blockIdx.x >> 3);   // nwg = 1024
  int bh = work >> 3, qt8 = work & 7;
  int b = bh >> 4, h = bh & 15;
  int bRow = b * SEQ;
  int hOff = h * 64;
  int q0 = qt8 * 128 + wid * 32;

  // Q fragments (B-operand): lane l15 = q-row, k = d = l4*8+e
  bf16x8 qr[2][2];
#pragma unroll
  for (int qt = 0; qt < 2; qt++) {
    const u16* qbase = qkv + (size_t)(bRow + q0 + qt * 16 + l15) * 3072 + hOff;
    qr[qt][0] = *(const bf16x8a*)(qbase + l4 * 8);
    qr[qt][1] = *(const bf16x8a*)(qbase + 32 + l4 * 8);
  }

  const float csc = 0.125f * 1.4426950408889634f;  // scale * log2(e)
  float mrow[2] = {-1e30f, -1e30f};
  float lsum[2] = {0.f, 0.f};
  f32x4 o[2][4] = {};   // O^T: [qt][dt], lane: q=l15 (col), d=dt*16+l4*4+r (row)
  u16* pw = Plds + wid * 16 * PSTR;

  for (int cc = 0; cc < 16; cc++) {
    int kv0 = cc * 64;
    __syncthreads();
    // stage K rows (row-major, padded)
#pragma unroll
    for (int i = 0; i < 2; i++) {
      int idx = i * 256 + t;
      int row = idx >> 3, ch = idx & 7;
      bf16x8 kk = *(const bf16x8a*)(qkv + (size_t)(bRow + kv0 + row) * 3072 + 1024 + hOff + ch * 8);
      *(bf16x8a*)&Ks[row * KSTR + ch * 8] = kk;
    }
    // stage V transposed (dc-staggered scalar writes)
#pragma unroll
    for (int i = 0; i < 2; i++) {
      int idx = i * 256 + t;
      int kv = idx >> 3, dc = idx & 7;
      bf16x8 vv = *(const bf16x8a*)(qkv + (size_t)(bRow + kv0 + kv) * 3072 + 2048 + hOff + dc * 8);
#pragma unroll
      for (int j = 0; j < 8; j++) {
        int jj = (j + dc) & 7;
        Vt[(dc * 8 + jj) * VSTR + kv] = ((const u16*)&vv)[jj];
      }
    }
    __syncthreads();

    // K A-fragments: lane l15 = kv-row, k = d
    bf16x8 ak[4][2];
#pragma unroll
    for (int kt = 0; kt < 4; kt++) {
      ak[kt][0] = *(const bf16x8a*)&Ks[(kt * 16 + l15) * KSTR + l4 * 8];
      ak[kt][1] = *(const bf16x8a*)&Ks[(kt * 16 + l15) * KSTR + 32 + l4 * 8];
    }
    // S^T = K . Q^T (raw, unscaled)
    f32x4 st[2][4];
#pragma unroll
    for (int qt = 0; qt < 2; qt++)
#pragma unroll
      for (int kt = 0; kt < 4; kt++) {
        f32x4 z = {0.f, 0.f, 0.f, 0.f};
        z = __builtin_amdgcn_mfma_f32_16x16x32_bf16(ak[kt][0], qr[qt][0], z, 0, 0, 0);
        z = __builtin_amdgcn_mfma_f32_16x16x32_bf16(ak[kt][1], qr[qt][1], z, 0, 0, 0);
        st[qt][kt] = z;
      }
    // V^T A-fragments: lane l15 = d-row, k = kv
    bf16x8 av[4][2];
#pragma unroll
    for (int dt = 0; dt < 4; dt++) {
      av[dt][0] = *(const bf16x8a*)&Vt[(dt * 16 + l15) * VSTR + l4 * 8];
      av[dt][1] = *(const bf16x8a*)&Vt[(dt * 16 + l15) * VSTR + 32 + l4 * 8];
    }

#pragma unroll
    for (int qt = 0; qt < 2; qt++) {
      float mx = st[qt][0][0];
#pragma unroll
      for (int kt = 0; kt < 4; kt++)
#pragma unroll
        for (int r = 0; r < 4; r++) mx = fmaxf(mx, st[qt][kt][r]);
      mx = fmaxf(mx, __shfl_xor(mx, 16));
      mx = fmaxf(mx, __shfl_xor(mx, 32));
      float mn = fmaxf(mrow[qt], mx * csc);
      float al = exp2_hw(mrow[qt] - mn);
      mrow[qt] = mn;
      float rs = 0.f;
#pragma unroll
      for (int kt = 0; kt < 4; kt++)
#pragma unroll
        for (int r = 0; r < 4; r++) {
          float p = exp2_hw(__builtin_fmaf(st[qt][kt][r], csc, -mn));
          st[qt][kt][r] = p;
          rs += p;
        }
      rs += __shfl_xor(rs, 16);
      rs += __shfl_xor(rs, 32);
      lsum[qt] = lsum[qt] * al + rs;
#pragma unroll
      for (int dt = 0; dt < 4; dt++) o[qt][dt] *= al;
      // P -> LDS row q=l15 via packed bf16 writes (may_alias: keeps TBAA ordering)
#pragma unroll
      for (int kt = 0; kt < 4; kt++) {
#pragma unroll
        for (int hh = 0; hh < 2; hh++) {
          uint32_t pk = cvt_pk_bf16(st[qt][kt][2 * hh], st[qt][kt][2 * hh + 1]);
          *(u32a*)&pw[l15 * PSTR + kt * 16 + l4 * 4 + 2 * hh] = pk;
        }
      }
      // hard fence: P writes must complete before P fragment reads (rule 18 pattern)
      asm volatile("s_waitcnt lgkmcnt(0)" ::: "memory");
      __builtin_amdgcn_sched_barrier(0);
      // P B-fragments: lane l15 = q-row, k = kv
      bf16x8 bp0 = *(const bf16x8a*)&pw[l15 * PSTR + l4 * 8];
      bf16x8 bp1 = *(const bf16x8a*)&pw[l15 * PSTR + 32 + l4 * 8];
#pragma unroll
      for (int dt = 0; dt < 4; dt++) {
        o[qt][dt] = __builtin_amdgcn_mfma_f32_16x16x32_bf16(av[dt][0], bp0, o[qt][dt], 0, 0, 0);
        o[qt][dt] = __builtin_amdgcn_mfma_f32_16x16x32_bf16(av[dt][1], bp1, o[qt][dt], 0, 0, 0);
      }
      // P reads of this qt must finish before next qt overwrites pw
      asm volatile("s_waitcnt lgkmcnt(0)" ::: "memory");
      __builtin_amdgcn_sched_barrier(0);
    }
  }
  // epilogue: O^T lane holds q=l15, d = dt*16 + l4*4 + {0..3}
#pragma unroll
  for (int qt = 0; qt < 2; qt++) {
    float inv = 1.f / lsum[qt];
    u16* orow = O + (size_t)(bRow + q0 + qt * 16 + l15) * HID + hOff;
#pragma unroll
    for (int dt = 0; dt < 4; dt++) {
      uint2 w;
      w.x = cvt_pk_bf16(o[qt][dt][0] * inv, o[qt][dt][1] * inv);
      w.y = cvt_pk_bf16(o[qt][dt][2] * inv, o[qt][dt][3] * inv);
      *(uint2*)(orow + dt * 16 + l4 * 4) = w;
    }
  }
}

// ---------- launch ----------
extern "C" void kernel_launch(void* const* d_in, const int* in_sizes, int n_in,
                              void* d_out, int out_size, void* d_ws, size_t ws_size,
                              hipStream_t stream) {
  const float* x      = (const float*)d_in[0];
  const float* c      = (const float*)d_in[1];
  const float* W_qkv  = (const float*)d_in[2];
  const float* b_qkv  = (const float*)d_in[3];
  const float* W_proj = (const float*)d_in[4];
  const float* b_proj = (const float*)d_in[5];
  const float* W_fc1  = (const float*)d_in[6];
  const float* b_fc1  = (const float*)d_in[7];
  const float* W_fc2  = (const float*)d_in[8];
  const float* b_fc2  = (const float*)d_in[9];
  const float* W_ada  = (const float*)d_in[10];
  const float* b_ada  = (const float*)d_in[11];
  float* out = (float*)d_out;
  char* ws = (char*)d_ws;

  // workspace layout (bytes)
  float* ada  = (float*)(ws + 0);            // 8x6144 f32
  u16* WtQKV  = (u16*)(ws + 196608);         // 3072x1024 bf16
  u16* WtP    = (u16*)(ws + 6488064);        // 1024x1024 bf16
  u16* WtF1   = (u16*)(ws + 8585216);        // 4096x1024 bf16
  u16* WtF2   = (u16*)(ws + 16973824);       // 1024x4096 bf16
  u16* hbuf   = (u16*)(ws + 25362432);       // 8192x1024 bf16 (h / attnO / h2)
  u16* big    = (u16*)(ws + 42139648);       // 8192x4096 bf16 max (qkv / gelu-out)
  // ada split-K partials live inside `big` (only used before qkv GEMM writes it)
  float* apart = (float*)(ws + 42139648);    // 32x8x6144 f32 = 6.29 MB

  transpose_bf16<<<dim3(3072 / 32, 1024 / 32), 256, 0, stream>>>(W_qkv, WtQKV, 1024, 3072);
  transpose_bf16<<<dim3(1024 / 32, 1024 / 32), 256, 0, stream>>>(W_proj, WtP, 1024, 1024);
  transpose_bf16<<<dim3(4096 / 32, 1024 / 32), 256, 0, stream>>>(W_fc1, WtF1, 1024, 4096);
  transpose_bf16<<<dim3(1024 / 32, 4096 / 32), 256, 0, stream>>>(W_fc2, WtF2, 4096, 1024);
  ada_part<<<dim3(ADA_N / 256, KCH), 256, 0, stream>>>(c, W_ada, apart);
  ada_reduce<<<(BATCH * ADA_N) / 256, 256, 0, stream>>>(apart, b_ada, ada);
  ln_mod<<<8192, 256, 0, stream>>>(x, ada, 0, 1024, hbuf);
  // qkv: 64 m-tiles x 24 n-tiles = 1536 blocks
  gemm2<0><<<1536, 256, 0, stream>>>(hbuf, WtQKV, b_qkv, big, nullptr, nullptr, 3072, 1024);
  attn_kernel<<<1024, 256, 0, stream>>>(big, hbuf);
  // proj: 64 x 8 = 512 blocks
  gemm2<2><<<512, 256, 0, stream>>>(hbuf, WtP, b_proj, out, x, ada + 2048, 1024, 1024);
  ln_mod<<<8192, 256, 0, stream>>>(out, ada, 3072, 4096, hbuf);
  // fc1: 64 x 32 = 2048 blocks
  gemm2<1><<<2048, 256, 0, stream>>>(hbuf, WtF1, b_fc1, big, nullptr, nullptr, 4096, 1024);
  // fc2: 64 x 8 = 512 blocks, K=4096
  gemm2<2><<<512, 256, 0, stream>>>(big, WtF2, b_fc2, out, out, ada + 5120, 1024, 4096);
}

// Round 9
// 426.130 us; speedup vs baseline: 1.0652x; 1.0085x over previous
//
#include <hip/hip_runtime.h>
#include <stdint.h>

typedef unsigned short u16;
typedef __attribute__((ext_vector_type(4))) float f32x4;
typedef __attribute__((ext_vector_type(8))) short bf16x8;
typedef bf16x8 bf16x8a __attribute__((may_alias));
typedef uint32_t u32a __attribute__((may_alias));

#define HID 1024
#define MLPD 4096
#define TEMB 1024
#define ADA_N 6144
#define SEQ 1024
#define BATCH 8
#define KCH 32          // ada split-K chunks
#define KCHLEN (TEMB / KCH)

// ---------- helpers ----------
__device__ __forceinline__ u16 f2bf_bits(float f) {
  uint32_t u = __float_as_uint(f);
  uint32_t r = (u + 0x7FFFu + ((u >> 16) & 1u)) >> 16;
  return (u16)r;
}

__device__ __forceinline__ float bf2f(u16 b) {
  return __uint_as_float(((uint32_t)b) << 16);
}

__device__ __forceinline__ uint32_t cvt_pk_bf16(float lo, float hi) {
  uint32_t r;
  asm("v_cvt_pk_bf16_f32 %0, %1, %2" : "=v"(r) : "v"(lo), "v"(hi));
  return r;
}

__device__ __forceinline__ float exp2_hw(float x) {
#if __has_builtin(__builtin_amdgcn_exp2f)
  return __builtin_amdgcn_exp2f(x);
#else
  return exp2f(x);
#endif
}

__device__ __forceinline__ void async_copy16(void* lds_dst, const void* g_src) {
  __builtin_amdgcn_global_load_lds(
      (const __attribute__((address_space(1))) void*)(uintptr_t)g_src,
      (__attribute__((address_space(3))) void*)(uint32_t)(uintptr_t)lds_dst,
      16, 0, 0);
}

__device__ __forceinline__ float gelu_tanh(float v) {
  float u = 0.7978845608028654f * (v + 0.044715f * v * v * v);
  float e = __expf(2.f * u);
  return v * e / (e + 1.f);   // = 0.5*v*(1+tanh(u))
}

// ---------- weight transpose fp32(KxN) -> bf16(NxK) ----------
__global__ __launch_bounds__(256) void transpose_bf16(const float* __restrict__ W,
                                                      u16* __restrict__ Wt, int K, int N) {
  __shared__ float tile[32][33];
  int n0 = blockIdx.x * 32, k0 = blockIdx.y * 32;
  int tx = threadIdx.x & 31, ty = threadIdx.x >> 5;   // 32 x 8
#pragma unroll
  for (int i = 0; i < 4; i++)
    tile[ty + i * 8][tx] = W[(size_t)(k0 + ty + i * 8) * N + n0 + tx];
  __syncthreads();
#pragma unroll
  for (int i = 0; i < 4; i++)
    Wt[(size_t)(n0 + ty + i * 8) * K + k0 + tx] = f2bf_bits(tile[tx][ty + i * 8]);
}

// ---------- ada split-K ----------
__global__ __launch_bounds__(256) void ada_part(const float* __restrict__ c,
                                                const float* __restrict__ W,
                                                float* __restrict__ part) {
  __shared__ float sc[BATCH * KCHLEN];
  int t = threadIdx.x;
  int col = blockIdx.x * 256 + t;
  int kc = blockIdx.y;
  int k0 = kc * KCHLEN;
  for (int i = t; i < BATCH * KCHLEN; i += 256) {
    int b = i >> 5, kk = i & (KCHLEN - 1);
    float v = c[b * TEMB + k0 + kk];
    sc[i] = v / (1.f + __expf(-v));
  }
  __syncthreads();
  float acc[BATCH] = {};
  for (int kk = 0; kk < KCHLEN; kk++) {
    float w = W[(size_t)(k0 + kk) * ADA_N + col];
#pragma unroll
    for (int b = 0; b < BATCH; b++) acc[b] += sc[b * KCHLEN + kk] * w;
  }
#pragma unroll
  for (int b = 0; b < BATCH; b++)
    part[((size_t)kc * BATCH + b) * ADA_N + col] = acc[b];
}

__global__ __launch_bounds__(256) void ada_reduce(const float* __restrict__ part,
                                                  const float* __restrict__ bias,
                                                  float* __restrict__ out) {
  int i = blockIdx.x * 256 + threadIdx.x;   // over 8*6144
  int col = i % ADA_N, b = i / ADA_N;
  float s = bias[col];
#pragma unroll
  for (int kc = 0; kc < KCH; kc++)
    s += part[((size_t)kc * BATCH + b) * ADA_N + col];
  out[(size_t)b * ADA_N + col] = s;
}

// ---------- fused LayerNorm + modulate -> bf16 ----------
__global__ __launch_bounds__(256) void ln_mod(const float* __restrict__ x,
                                              const float* __restrict__ ada,
                                              int shift_off, int scale_off,
                                              u16* __restrict__ h) {
  int row = blockIdx.x;        // 0..8191
  int bb = row >> 10;
  int t = threadIdx.x;
  const float4 v = ((const float4*)(x + (size_t)row * HID))[t];
  float s = v.x + v.y + v.z + v.w;
  float sq = v.x * v.x + v.y * v.y + v.z * v.z + v.w * v.w;
#pragma unroll
  for (int off = 32; off >= 1; off >>= 1) {
    s += __shfl_xor(s, off);
    sq += __shfl_xor(sq, off);
  }
  __shared__ float red[8];
  int wid = t >> 6;
  if ((t & 63) == 0) { red[wid] = s; red[4 + wid] = sq; }
  __syncthreads();
  s = red[0] + red[1] + red[2] + red[3];
  sq = red[4] + red[5] + red[6] + red[7];
  float mu = s * (1.0f / HID);
  float rs = rsqrtf(sq * (1.0f / HID) - mu * mu + 1e-6f);
  const float4 sc = ((const float4*)(ada + (size_t)bb * ADA_N + scale_off))[t];
  const float4 sh = ((const float4*)(ada + (size_t)bb * ADA_N + shift_off))[t];
  ushort4 o;
  o.x = f2bf_bits((v.x - mu) * rs * (1.f + sc.x) + sh.x);
  o.y = f2bf_bits((v.y - mu) * rs * (1.f + sc.y) + sh.y);
  o.z = f2bf_bits((v.z - mu) * rs * (1.f + sc.z) + sh.z);
  o.w = f2bf_bits((v.w - mu) * rs * (1.f + sc.w) + sh.w);
  ((ushort4*)(h + (size_t)row * HID))[t] = o;
}

// ---------- 3-buffer deep-pipelined 128x128 bf16 GEMM ----------
// C(M x N) = A(M x K) * Bt(N x K)^T + bias. 256 thr / 4 waves (2x2), BK=32.
// Pipeline depth 2: iteration ts stages tile ts+2 into the buffer freed at
// ts-1's closing barrier, then waits COUNTED vmcnt(8) (tiles ts+1 and ts+2 = 8
// loads stay in flight across the barrier). 2-iteration prefetch lead covers
// L2-miss/HBM latency (~900 cyc) that the old 1-tile lead exposed.
// LDS 48 KB staging (3 x 16 KB) -> 3 blocks/CU; epilogue reuses it (33.8 KB).
// Swizzle key (row>>1)&3 on both gld-lds source and ds_read (rule 21).
// EPI: 0 = bf16 out, 1 = gelu -> bf16 out, 2 = f32 out = resid + gate*(acc+bias)

__device__ __forceinline__ void stage32(u16* dst, const u16* gsrc, int K, int koff, int t) {
#pragma unroll
  for (int i = 0; i < 2; ++i) {
    int slot = i * 256 + t;
    int row = slot >> 2, cp = slot & 3;
    const u16* src = gsrc + (size_t)row * K + koff + ((cp ^ ((row >> 1) & 3)) << 3);
    async_copy16(dst + slot * 8, src);
  }
}

#define LDSRD32(buf, row) \
  (*(const bf16x8a*)&(buf)[(row) * 32 + ((l4 ^ (((row) >> 1) & 3)) << 3)])

template <int EPI>
__global__ __launch_bounds__(256) void gemm2(const u16* __restrict__ A,
                                             const u16* __restrict__ Bt,
                                             const float* __restrict__ bias,
                                             void* __restrict__ Cout,
                                             const float* __restrict__ resid,
                                             const float* __restrict__ gate,
                                             int N, int K) {
  __shared__ u16 lds[24576];           // 48 KB: 3 buffers of (A 4096 | B 4096) u16
  int t = threadIdx.x;
  int lane = t & 63, wid = t >> 6;
  int l15 = lane & 15, l4 = lane >> 4;
  int wr = wid >> 1, wc = wid & 1;     // 2 x 2 waves; wave tile 64 x 64
  // XCD m-banding: each XCD owns 8 contiguous m-tiles; n sweeps within band.
  int lid = blockIdx.x;
  int xcd = lid & 7, win = lid >> 3;
  int m0 = (xcd * 8 + (win & 7)) * 128;
  int n0 = (win >> 3) * 128;

  const u16* Abase = A + (size_t)m0 * K;
  const u16* Bbase = Bt + (size_t)n0 * K;
  f32x4 acc[4][4] = {};

  u16 *b0 = lds, *b1 = lds + 8192, *b2 = lds + 16384;  // A at +0, B at +4096
  int nt = K / 32;
  // prologue: stage tiles 0 and 1 (8 loads/thread in flight)
  stage32(b0, Abase, K, 0, t);
  stage32(b0 + 4096, Bbase, K, 0, t);
  stage32(b1, Abase, K, 32, t);
  stage32(b1 + 4096, Bbase, K, 32, t);
  for (int ts = 0; ts < nt; ++ts) {
    // stage tile ts+2 into b2 (held tile ts-1; freed at ts-1's closing barrier)
    if (ts + 2 < nt) {
      stage32(b2, Abase, K, (ts + 2) * 32, t);
      stage32(b2 + 4096, Bbase, K, (ts + 2) * 32, t);
      asm volatile("s_waitcnt vmcnt(8)" ::: "memory");   // ts landed; ts+1, ts+2 in flight
    } else if (ts + 1 < nt) {
      asm volatile("s_waitcnt vmcnt(4)" ::: "memory");
    } else {
      asm volatile("s_waitcnt vmcnt(0)" ::: "memory");
    }
    __builtin_amdgcn_s_barrier();
    bf16x8 af[4], bfr[4];
#pragma unroll
    for (int mi = 0; mi < 4; ++mi)
      af[mi] = LDSRD32(b0, wr * 64 + mi * 16 + l15);
#pragma unroll
    for (int ni = 0; ni < 4; ++ni)
      bfr[ni] = LDSRD32(b0 + 4096, wc * 64 + ni * 16 + l15);
#pragma unroll
    for (int mi = 0; mi < 4; ++mi)
#pragma unroll
      for (int ni = 0; ni < 4; ++ni)
        acc[mi][ni] = __builtin_amdgcn_mfma_f32_16x16x32_bf16(af[mi], bfr[ni], acc[mi][ni], 0, 0, 0);
    asm volatile("" ::: "memory");
    __builtin_amdgcn_s_barrier();      // all waves' reads done -> b0 reusable
    u16* tp = b0; b0 = b1; b1 = b2; b2 = tp;
  }

  // ---- epilogue: acc -> bf16 -> LDS transpose -> 16-B coalesced stores ----
  const int EST = 132;                 // 128x132 u16 = 33792 B <= 48 KB
  int bb = m0 >> 10;                   // 128-row tile lies within one batch
#pragma unroll
  for (int ni = 0; ni < 4; ++ni) {
    int col = wc * 64 + ni * 16 + l15;
    float bv = bias[n0 + col];
    float gv = (EPI == 2) ? gate[(size_t)bb * ADA_N + n0 + col] : 0.f;
#pragma unroll
    for (int mi = 0; mi < 4; ++mi)
#pragma unroll
      for (int r = 0; r < 4; ++r) {
        int row = wr * 64 + mi * 16 + l4 * 4 + r;
        float v = acc[mi][ni][r] + bv;
        if (EPI == 1) v = gelu_tanh(v);
        if (EPI == 2) v = gv * v;
        lds[row * EST + col] = f2bf_bits(v);
      }
  }
  asm volatile("s_waitcnt lgkmcnt(0)" ::: "memory");
  __builtin_amdgcn_s_barrier();
  asm volatile("" ::: "memory");
  {
    int row = t >> 1, half = t & 1;    // 2 threads per 128-col row
    size_t grow = (size_t)(m0 + row) * N + n0 + half * 64;
#pragma unroll
    for (int j = 0; j < 8; ++j) {
      bf16x8 v = *(const bf16x8a*)&lds[row * EST + half * 64 + j * 8];
      if (EPI == 2) {
        const float4* rp = (const float4*)&resid[grow + j * 8];
        float4 o0 = rp[0], o1 = rp[1];
        o0.x += bf2f((u16)v[0]); o0.y += bf2f((u16)v[1]);
        o0.z += bf2f((u16)v[2]); o0.w += bf2f((u16)v[3]);
        o1.x += bf2f((u16)v[4]); o1.y += bf2f((u16)v[5]);
        o1.z += bf2f((u16)v[6]); o1.w += bf2f((u16)v[7]);
        float4* op = (float4*)((float*)Cout + grow + j * 8);
        op[0] = o0; op[1] = o1;
      } else {
        *(bf16x8a*)((u16*)Cout + grow + j * 8) = v;
      }
    }
  }
}

// ---------- flash attention, swapped-operand structure ----------
__global__ __launch_bounds__(256, 3) void attn_kernel(const u16* __restrict__ qkv,
                                                      u16* __restrict__ O) {
  const int KSTR = 72, VSTR = 72, PSTR = 72;  // u16 strides, 16B-aligned rows
  __shared__ u16 Ks[64 * 72];       // K chunk rows [kv][d]
  __shared__ u16 Vt[64 * 72];       // V chunk transposed [d][kv]
  __shared__ u16 Plds[4 * 16 * 72]; // per-wave P rows [q][kv]
  int t = threadIdx.x, lane = t & 63, wid = t >> 6;
  int l15 = lane & 15, l4 = lane >> 4;
  // T1: all 8 q-tiles of one (b,h) + 16 consecutive bh land on one XCD (KV L2 reuse)
  int work = ((blockIdx.x & 7) << 7) + (blockIdx.x >> 3);   // nwg = 1024
  int bh = work >> 3, qt8 = work & 7;
  int b = bh >> 4, h = bh & 15;
  int bRow = b * SEQ;
  int hOff = h * 64;
  int q0 = qt8 * 128 + wid * 32;

  // Q fragments (B-operand): lane l15 = q-row, k = d = l4*8+e
  bf16x8 qr[2][2];
#pragma unroll
  for (int qt = 0; qt < 2; qt++) {
    const u16* qbase = qkv + (size_t)(bRow + q0 + qt * 16 + l15) * 3072 + hOff;
    qr[qt][0] = *(const bf16x8a*)(qbase + l4 * 8);
    qr[qt][1] = *(const bf16x8a*)(qbase + 32 + l4 * 8);
  }

  const float csc = 0.125f * 1.4426950408889634f;  // scale * log2(e)
  float mrow[2] = {-1e30f, -1e30f};
  float lsum[2] = {0.f, 0.f};
  f32x4 o[2][4] = {};   // O^T: [qt][dt], lane: q=l15 (col), d=dt*16+l4*4+r (row)
  u16* pw = Plds + wid * 16 * PSTR;

  for (int cc = 0; cc < 16; cc++) {
    int kv0 = cc * 64;
    __syncthreads();
    // stage K rows (row-major, padded)
#pragma unroll
    for (int i = 0; i < 2; i++) {
      int idx = i * 256 + t;
      int row = idx >> 3, ch = idx & 7;
      bf16x8 kk = *(const bf16x8a*)(qkv + (size_t)(bRow + kv0 + row) * 3072 + 1024 + hOff + ch * 8);
      *(bf16x8a*)&Ks[row * KSTR + ch * 8] = kk;
    }
    // stage V transposed (dc-staggered scalar writes)
#pragma unroll
    for (int i = 0; i < 2; i++) {
      int idx = i * 256 + t;
      int kv = idx >> 3, dc = idx & 7;
      bf16x8 vv = *(const bf16x8a*)(qkv + (size_t)(bRow + kv0 + kv) * 3072 + 2048 + hOff + dc * 8);
#pragma unroll
      for (int j = 0; j < 8; j++) {
        int jj = (j + dc) & 7;
        Vt[(dc * 8 + jj) * VSTR + kv] = ((const u16*)&vv)[jj];
      }
    }
    __syncthreads();

    // K A-fragments: lane l15 = kv-row, k = d
    bf16x8 ak[4][2];
#pragma unroll
    for (int kt = 0; kt < 4; kt++) {
      ak[kt][0] = *(const bf16x8a*)&Ks[(kt * 16 + l15) * KSTR + l4 * 8];
      ak[kt][1] = *(const bf16x8a*)&Ks[(kt * 16 + l15) * KSTR + 32 + l4 * 8];
    }
    // S^T = K . Q^T (raw, unscaled)
    f32x4 st[2][4];
#pragma unroll
    for (int qt = 0; qt < 2; qt++)
#pragma unroll
      for (int kt = 0; kt < 4; kt++) {
        f32x4 z = {0.f, 0.f, 0.f, 0.f};
        z = __builtin_amdgcn_mfma_f32_16x16x32_bf16(ak[kt][0], qr[qt][0], z, 0, 0, 0);
        z = __builtin_amdgcn_mfma_f32_16x16x32_bf16(ak[kt][1], qr[qt][1], z, 0, 0, 0);
        st[qt][kt] = z;
      }
    // V^T A-fragments: lane l15 = d-row, k = kv
    bf16x8 av[4][2];
#pragma unroll
    for (int dt = 0; dt < 4; dt++) {
      av[dt][0] = *(const bf16x8a*)&Vt[(dt * 16 + l15) * VSTR + l4 * 8];
      av[dt][1] = *(const bf16x8a*)&Vt[(dt * 16 + l15) * VSTR + 32 + l4 * 8];
    }

#pragma unroll
    for (int qt = 0; qt < 2; qt++) {
      float mx = st[qt][0][0];
#pragma unroll
      for (int kt = 0; kt < 4; kt++)
#pragma unroll
        for (int r = 0; r < 4; r++) mx = fmaxf(mx, st[qt][kt][r]);
      mx = fmaxf(mx, __shfl_xor(mx, 16));
      mx = fmaxf(mx, __shfl_xor(mx, 32));
      float mn = fmaxf(mrow[qt], mx * csc);
      float al = exp2_hw(mrow[qt] - mn);
      mrow[qt] = mn;
      float rs = 0.f;
#pragma unroll
      for (int kt = 0; kt < 4; kt++)
#pragma unroll
        for (int r = 0; r < 4; r++) {
          float p = exp2_hw(__builtin_fmaf(st[qt][kt][r], csc, -mn));
          st[qt][kt][r] = p;
          rs += p;
        }
      rs += __shfl_xor(rs, 16);
      rs += __shfl_xor(rs, 32);
      lsum[qt] = lsum[qt] * al + rs;
#pragma unroll
      for (int dt = 0; dt < 4; dt++) o[qt][dt] *= al;
      // P -> LDS row q=l15 via packed bf16 writes (may_alias: keeps TBAA ordering)
#pragma unroll
      for (int kt = 0; kt < 4; kt++) {
#pragma unroll
        for (int hh = 0; hh < 2; hh++) {
          uint32_t pk = cvt_pk_bf16(st[qt][kt][2 * hh], st[qt][kt][2 * hh + 1]);
          *(u32a*)&pw[l15 * PSTR + kt * 16 + l4 * 4 + 2 * hh] = pk;
        }
      }
      // hard fence: P writes must complete before P fragment reads (rule 18 pattern)
      asm volatile("s_waitcnt lgkmcnt(0)" ::: "memory");
      __builtin_amdgcn_sched_barrier(0);
      // P B-fragments: lane l15 = q-row, k = kv
      bf16x8 bp0 = *(const bf16x8a*)&pw[l15 * PSTR + l4 * 8];
      bf16x8 bp1 = *(const bf16x8a*)&pw[l15 * PSTR + 32 + l4 * 8];
#pragma unroll
      for (int dt = 0; dt < 4; dt++) {
        o[qt][dt] = __builtin_amdgcn_mfma_f32_16x16x32_bf16(av[dt][0], bp0, o[qt][dt], 0, 0, 0);
        o[qt][dt] = __builtin_amdgcn_mfma_f32_16x16x32_bf16(av[dt][1], bp1, o[qt][dt], 0, 0, 0);
      }
      // P reads of this qt must finish before next qt overwrites pw
      asm volatile("s_waitcnt lgkmcnt(0)" ::: "memory");
      __builtin_amdgcn_sched_barrier(0);
    }
  }
  // epilogue: O^T lane holds q=l15, d = dt*16 + l4*4 + {0..3}
#pragma unroll
  for (int qt = 0; qt < 2; qt++) {
    float inv = 1.f / lsum[qt];
    u16* orow = O + (size_t)(bRow + q0 + qt * 16 + l15) * HID + hOff;
#pragma unroll
    for (int dt = 0; dt < 4; dt++) {
      uint2 w;
      w.x = cvt_pk_bf16(o[qt][dt][0] * inv, o[qt][dt][1] * inv);
      w.y = cvt_pk_bf16(o[qt][dt][2] * inv, o[qt][dt][3] * inv);
      *(uint2*)(orow + dt * 16 + l4 * 4) = w;
    }
  }
}

// ---------- launch ----------
extern "C" void kernel_launch(void* const* d_in, const int* in_sizes, int n_in,
                              void* d_out, int out_size, void* d_ws, size_t ws_size,
                              hipStream_t stream) {
  const float* x      = (const float*)d_in[0];
  const float* c      = (const float*)d_in[1];
  const float* W_qkv  = (const float*)d_in[2];
  const float* b_qkv  = (const float*)d_in[3];
  const float* W_proj = (const float*)d_in[4];
  const float* b_proj = (const float*)d_in[5];
  const float* W_fc1  = (const float*)d_in[6];
  const float* b_fc1  = (const float*)d_in[7];
  const float* W_fc2  = (const float*)d_in[8];
  const float* b_fc2  = (const float*)d_in[9];
  const float* W_ada  = (const float*)d_in[10];
  const float* b_ada  = (const float*)d_in[11];
  float* out = (float*)d_out;
  char* ws = (char*)d_ws;

  // workspace layout (bytes)
  float* ada  = (float*)(ws + 0);            // 8x6144 f32
  u16* WtQKV  = (u16*)(ws + 196608);         // 3072x1024 bf16
  u16* WtP    = (u16*)(ws + 6488064);        // 1024x1024 bf16
  u16* WtF1   = (u16*)(ws + 8585216);        // 4096x1024 bf16
  u16* WtF2   = (u16*)(ws + 16973824);       // 1024x4096 bf16
  u16* hbuf   = (u16*)(ws + 25362432);       // 8192x1024 bf16 (h / attnO / h2)
  u16* big    = (u16*)(ws + 42139648);       // 8192x4096 bf16 max (qkv / gelu-out)
  // ada split-K partials live inside `big` (only used before qkv GEMM writes it)
  float* apart = (float*)(ws + 42139648);    // 32x8x6144 f32 = 6.29 MB

  transpose_bf16<<<dim3(3072 / 32, 1024 / 32), 256, 0, stream>>>(W_qkv, WtQKV, 1024, 3072);
  transpose_bf16<<<dim3(1024 / 32, 1024 / 32), 256, 0, stream>>>(W_proj, WtP, 1024, 1024);
  transpose_bf16<<<dim3(4096 / 32, 1024 / 32), 256, 0, stream>>>(W_fc1, WtF1, 1024, 4096);
  transpose_bf16<<<dim3(1024 / 32, 4096 / 32), 256, 0, stream>>>(W_fc2, WtF2, 4096, 1024);
  ada_part<<<dim3(ADA_N / 256, KCH), 256, 0, stream>>>(c, W_ada, apart);
  ada_reduce<<<(BATCH * ADA_N) / 256, 256, 0, stream>>>(apart, b_ada, ada);
  ln_mod<<<8192, 256, 0, stream>>>(x, ada, 0, 1024, hbuf);
  // qkv: 64 m-tiles x 24 n-tiles = 1536 blocks
  gemm2<0><<<1536, 256, 0, stream>>>(hbuf, WtQKV, b_qkv, big, nullptr, nullptr, 3072, 1024);
  attn_kernel<<<1024, 256, 0, stream>>>(big, hbuf);
  // proj: 64 x 8 = 512 blocks
  gemm2<2><<<512, 256, 0, stream>>>(hbuf, WtP, b_proj, out, x, ada + 2048, 1024, 1024);
  ln_mod<<<8192, 256, 0, stream>>>(out, ada, 3072, 4096, hbuf);
  // fc1: 64 x 32 = 2048 blocks
  gemm2<1><<<2048, 256, 0, stream>>>(hbuf, WtF1, b_fc1, big, nullptr, nullptr, 4096, 1024);
  // fc2: 64 x 8 = 512 blocks, K=4096
  gemm2<2><<<512, 256, 0, stream>>>(big, WtF2, b_fc2, out, out, ada + 5120, 1024, 4096);
}